// Round 2
// baseline (1819.738 us; speedup 1.0000x reference)
//
#include <hip/hip_runtime.h>

typedef __attribute__((ext_vector_type(8))) __bf16 bf16x8;
typedef __attribute__((ext_vector_type(4))) float  f32x4;

#define DEVFN __device__ __forceinline__

constexpr int B = 256, I = 256, H = 512, S = 64;
constexpr int G4H = 4 * H;   // 2048 encoder gate cols
constexpr int G4I = 4 * I;   // 1024 decoder gate cols

struct Params {
  const float* x;        // [B][I][S]      fp32
  const float* Wih_enc;  // [S][4H][I]     fp32
  const float* Whh_enc;  // [S][4H][H]     fp32
  const float* bih_enc;  // [S][4H]
  const float* bhh_enc;  // [S][4H]
  const float* Wih_dec;  // [S][4I][H]     fp32
  const float* bih_dec;  // [S][4I]
  const float* bhh_dec;  // [S][4I]
  __bf16* xT;             // [S][B][I]  bf16
  float*  h32a; float*  h32b;   // [B][H] ping-pong (fp32 h for cell update)
  __bf16* h16a; __bf16* h16b;   // [B][H] ping-pong (bf16 h for MFMA)
  __bf16* enc;            // [S][B][H]  bf16: elu(h_t), then AR-filtered in place
  float*  hd;             // [S][B][I]  fp32
  float*  out;            // [B][I][S]  fp32
};

DEVFN float sigmoidf_(float x) { return 1.0f / (1.0f + __expf(-x)); }
DEVFN float tanhf_(float x) { float e = __expf(2.0f * x); return 1.0f - 2.0f / (e + 1.0f); }

// load 8 fp32, convert to bf16x8 (for MFMA operands)
DEVFN bf16x8 loadw8(const float* p) {
  float4 a = *(const float4*)p;
  float4 b = *(const float4*)(p + 4);
  bf16x8 r;
  r[0] = (__bf16)a.x; r[1] = (__bf16)a.y; r[2] = (__bf16)a.z; r[3] = (__bf16)a.w;
  r[4] = (__bf16)b.x; r[5] = (__bf16)b.y; r[6] = (__bf16)b.z; r[7] = (__bf16)b.w;
  return r;
}

// ---------------- phase: transpose x[B][I][S] (fp32) -> xT[S][B][I] (bf16) ----
// job in [0,1024): b = job>>2, i0 = (job&3)*64. Block = 512 thr.
DEVFN void phase_transpose(const Params& P, int job, float* smemf) {
  __bf16* tile = (__bf16*)smemf;            // [64][66] bf16 = 8448 B
  const int tid = threadIdx.x;
  const int b = job >> 2, i0 = (job & 3) * 64;
#pragma unroll
  for (int rep = 0; rep < 8; ++rep) {
    int idx = tid + rep * 512;
    int ii = idx >> 6, tt = idx & 63;       // coalesced along t
    tile[ii * 66 + tt] = (__bf16)P.x[((size_t)(b * I + i0 + ii)) * S + tt];
  }
  __syncthreads();
#pragma unroll
  for (int rep = 0; rep < 8; ++rep) {
    int idx = tid + rep * 512;
    int tt = idx >> 6, ii = idx & 63;       // coalesced along i
    P.xT[((size_t)tt * B + b) * I + i0 + ii] = tile[ii * 66 + tt];
  }
}

// ---------------- phase: one encoder LSTM step t ----------------
// job in [0,256): 16 blocks sharing a weight slice (same jt, all bt) differ by
// 8 in blockIdx -> same XCD (blockIdx%8). Block: 512 thr = 8 waves;
// tile = 16 b-rows x (4 gates x 32 j-cols), one 16x16 MFMA tile per wave x2.
DEVFN void phase_step(const Params& P, int t, int job, float* smem) {
  const int tid = threadIdx.x;
  const int g = job >> 7, r = job & 7, bt = (job >> 3) & 15;
  const int jt = g * 8 + r;                 // [0,16)
  const int b0 = bt * 16, j0 = jt * 32;
  const int wave = tid >> 6, lane = tid & 63;
  const int e = wave >> 1, ct = wave & 1;   // gate e in {i,f,g,o}, col-tile ct
  const int ncol = lane & 15, quad = lane >> 4;
  const int gcol = e * H + j0 + ct * 16 + ncol;   // gate column in [0,2048)
  const float*  h32r = (t & 1) ? P.h32b : P.h32a;
  float*        h32w = (t & 1) ? P.h32a : P.h32b;
  const __bf16* h16r = (t & 1) ? P.h16b : P.h16a;
  __bf16*       h16w = (t & 1) ? P.h16a : P.h16b;

  float bias = P.bih_enc[t * G4H + gcol] + P.bhh_enc[t * G4H + gcol];
  f32x4 acc = {bias, bias, bias, bias};
  const int m = ncol;                        // A-frag row within tile
  // K part 1: x_t (K=256); A bf16 from xT, B fp32->bf16 from Wih_enc
  const __bf16* aRow1 = P.xT + ((size_t)t * B + b0 + m) * I + quad * 8;
  const float*  bRow1 = P.Wih_enc + ((size_t)t * G4H + gcol) * I + quad * 8;
#pragma unroll
  for (int kk = 0; kk < I; kk += 32) {
    bf16x8 af = *(const bf16x8*)(aRow1 + kk);
    bf16x8 bf = loadw8(bRow1 + kk);
    acc = __builtin_amdgcn_mfma_f32_16x16x32_bf16(af, bf, acc, 0, 0, 0);
  }
  // K part 2: h_{t-1} (K=512)
  const __bf16* aRow2 = h16r + (size_t)(b0 + m) * H + quad * 8;
  const float*  bRow2 = P.Whh_enc + ((size_t)t * G4H + gcol) * H + quad * 8;
#pragma unroll
  for (int kk = 0; kk < H; kk += 32) {
    bf16x8 af = *(const bf16x8*)(aRow2 + kk);
    bf16x8 bf = loadw8(bRow2 + kk);
    acc = __builtin_amdgcn_mfma_f32_16x16x32_bf16(af, bf, acc, 0, 0, 0);
  }
  // stash gate tiles: smem[(e*2+ct)*256 + row*16 + col]
  float* sm = smem + (e * 2 + ct) * 256;
#pragma unroll
  for (int rr = 0; rr < 4; ++rr) sm[(quad * 4 + rr) * 16 + ncol] = acc[rr];
  __syncthreads();
  // epilogue: 16 rows x 32 j = 512 outputs, one per thread
  {
    const int row = tid >> 5, j = tid & 31;
    const int o = (j >> 4) * 256 + row * 16 + (j & 15);
    float gi = smem[o], gf = smem[512 + o], gg = smem[1024 + o], go = smem[1536 + o];
    size_t hidx = (size_t)(b0 + row) * H + j0 + j;
    float hp = h32r[hidx];
    float c  = sigmoidf_(gf) * hp + sigmoidf_(gi) * tanhf_(gg);
    float hn = sigmoidf_(go) * tanhf_(c);
    h32w[hidx] = hn;
    h16w[hidx] = (__bf16)hn;
    float el = hn > 0.0f ? hn : (__expf(hn) - 1.0f);
    P.enc[((size_t)t * B + b0 + row) * H + j0 + j] = (__bf16)el;
  }
}

// ---------------- phase: AR filter over enc (in place, bf16, fp32 math) ------
// one thread per (b, h); 256 blocks x 512 threads = B*H.
DEVFN void phase_ar(const Params& P) {
  int gid = blockIdx.x * blockDim.x + threadIdx.x;
  int b = gid >> 9, hi = gid & 511;
  float prev = (float)P.enc[((size_t)60 * B + b) * H + hi];  // enc[-RES] original
#pragma unroll
  for (int a = 0; a < 16; ++a) {
    size_t idx = ((size_t)(4 * a) * B + b) * H + hi;
    float cur = (float)P.enc[idx];
    float nv = 0.5f * (cur + prev);          // ALPHA = 0.5
    P.enc[idx] = (__bf16)nv;
    prev = nv;
  }
}

// ---------------- phase: decoder gates -> hd (fp32) ----------------
// job in [0,2048): job = g*32 + bt*8 + r; (s,jt) = (g*8+r). 4 weight-sharing
// bt land on same XCD. Block tile: 64 b-rows x (3 gates {i,g,o} x 32 j).
DEVFN void phase_dec(const Params& P, int job, float* smem) {
  const int tid = threadIdx.x;
  const int g = job >> 5, bt = (job >> 3) & 3, r = job & 7;
  const int sjt = g * 8 + r;
  const int s = sjt >> 3, jt = sjt & 7;
  const int b0 = bt * 64, j0 = jt * 32;
  const int wave = tid >> 6, lane = tid & 63;
  const int rt = wave >> 1, chalf = wave & 1;
  const int ncol = lane & 15, quad = lane >> 4;
  const int arow = b0 + rt * 16 + ncol;
  const __bf16* aRow = P.enc + ((size_t)(63 - s) * B + arow) * H + quad * 8;

  f32x4 acc[3];
  int gcols[3];
#pragma unroll
  for (int cc = 0; cc < 3; ++cc) {
    const int c = chalf * 3 + cc;            // col-tile in [0,6)
    const int e3 = c >> 1;                   // 0,1,2 -> gates {i,g,o}
    const int gate = (e3 == 0) ? 0 : (e3 + 1);
    const int gcol = gate * I + j0 + (c & 1) * 16 + ncol;
    gcols[cc] = gcol;
    float bias = P.bih_dec[s * G4I + gcol] + P.bhh_dec[s * G4I + gcol];
    acc[cc] = {bias, bias, bias, bias};
  }
  const float* bBase = P.Wih_dec + (size_t)s * G4I * H + quad * 8;
#pragma unroll
  for (int kk = 0; kk < H; kk += 32) {
    bf16x8 af = *(const bf16x8*)(aRow + kk);
#pragma unroll
    for (int cc = 0; cc < 3; ++cc) {
      bf16x8 bf = loadw8(bBase + (size_t)gcols[cc] * H + kk);
      acc[cc] = __builtin_amdgcn_mfma_f32_16x16x32_bf16(af, bf, acc[cc], 0, 0, 0);
    }
  }
#pragma unroll
  for (int cc = 0; cc < 3; ++cc) {
    const int c = chalf * 3 + cc;
    const int e3 = c >> 1;
    const int jw = (c & 1) * 16 + ncol;
    float* sm = smem + e3 * 2048 + (rt * 16) * 32 + jw;
#pragma unroll
    for (int rr = 0; rr < 4; ++rr) sm[(quad * 4 + rr) * 32] = acc[cc][rr];
  }
  __syncthreads();
  // epilogue: 64 rows x 32 j, 4 per thread, vectorized fp32 store
  {
    const int row = tid >> 3, jb = (tid & 7) * 4;
    float tmp[4];
#pragma unroll
    for (int u = 0; u < 4; ++u) {
      int j = jb + u;
      float gi = smem[row * 32 + j];
      float gg = smem[2048 + row * 32 + j];
      float go = smem[4096 + row * 32 + j];
      float cv = sigmoidf_(gi) * tanhf_(gg);
      tmp[u] = sigmoidf_(go) * tanhf_(cv);
    }
    float* hout = &P.hd[((size_t)s * B + b0 + row) * I + j0 + jb];
    *(float4*)hout = make_float4(tmp[0], tmp[1], tmp[2], tmp[3]);
  }
}

// ---------------- phase: blockwise cumsum + tanh + transpose out (fp32) ------
// job in [0,1024): b = job>>2, i0 = (job&3)*64.
DEVFN void phase_out(const Params& P, int job, float* smem) {
  const int tid = threadIdx.x;
  const int b = job >> 2, i0 = (job & 3) * 64;
#pragma unroll
  for (int rep = 0; rep < 8; ++rep) {
    int idx = tid + rep * 512;
    int tt = idx >> 6, ii = idx & 63;
    smem[tt * 66 + ii] = P.hd[((size_t)tt * B + b) * I + i0 + ii];
  }
  __syncthreads();
#pragma unroll
  for (int rep = 0; rep < 2; ++rep) {
    int a = tid & 15;                        // cumsum group (RES=4)
    int ii = (tid >> 4) + rep * 32;          // i within strip
    float r0 = smem[(4 * a + 0) * 66 + ii];
    float r1 = r0 + smem[(4 * a + 1) * 66 + ii];
    float r2 = r1 + smem[(4 * a + 2) * 66 + ii];
    float r3 = r2 + smem[(4 * a + 3) * 66 + ii];
    // out[b][i][s] = tanh(run[63-s]); s = 60-4a+w corresponds to run[4a+3-w]
    float4 v = make_float4(tanhf_(r3), tanhf_(r2), tanhf_(r1), tanhf_(r0));
    *(float4*)&P.out[((size_t)(b * I + i0 + ii)) * S + (60 - 4 * a)] = v;
  }
}

// ---------------- kernels ----------------
__global__ __launch_bounds__(512) void k_transpose(Params P) {
  __shared__ float sm[2112];
  phase_transpose(P, blockIdx.x, sm);
}
__global__ __launch_bounds__(512) void k_step(Params P, int t) {
  __shared__ float sm[2048];
  phase_step(P, t, blockIdx.x, sm);
}
__global__ __launch_bounds__(512) void k_ar(Params P) { phase_ar(P); }
__global__ __launch_bounds__(512) void k_dec(Params P) {
  __shared__ float sm[6144];
  phase_dec(P, blockIdx.x, sm);
}
__global__ __launch_bounds__(512) void k_out(Params P) {
  __shared__ float sm[4224];
  phase_out(P, blockIdx.x, sm);
}

extern "C" void kernel_launch(void* const* d_in, const int* in_sizes, int n_in,
                              void* d_out, int out_size, void* d_ws, size_t ws_size,
                              hipStream_t stream) {
  (void)in_sizes; (void)n_in; (void)out_size; (void)ws_size;
  char* ws = (char*)d_ws;
  Params P;
  P.x       = (const float*)d_in[0];
  P.Wih_enc = (const float*)d_in[1];
  P.Whh_enc = (const float*)d_in[2];
  P.bih_enc = (const float*)d_in[3];
  P.bhh_enc = (const float*)d_in[4];
  P.Wih_dec = (const float*)d_in[5];
  // d_in[6] = Whh_dec: unused by the reference
  P.bih_dec = (const float*)d_in[7];
  P.bhh_dec = (const float*)d_in[8];

  size_t off = 0;
  P.xT   = (__bf16*)(ws + off); off += (size_t)S * B * I * 2;      //  8,388,608
  P.h32a = (float*) (ws + off); off += (size_t)B * H * 4;          //    524,288
  P.h16a = (__bf16*)(ws + off); off += (size_t)B * H * 2;          //    262,144
  P.h32b = (float*) (ws + off); off += (size_t)B * H * 4;
  P.h16b = (__bf16*)(ws + off); off += (size_t)B * H * 2;
  P.enc  = (__bf16*)(ws + off); off += (size_t)S * B * H * 2;      // 16,777,216
  P.hd   = (float*) (ws + off); off += (size_t)S * B * I * 4;      // 16,777,216
  P.out  = (float*)d_out;

  // zero h slot 0 (h32a + h16a are contiguous: 512KB + 256KB)
  hipMemsetAsync((char*)P.h32a, 0, (size_t)B * H * 4 + (size_t)B * H * 2, stream);

  k_transpose<<<1024, 512, 0, stream>>>(P);
  for (int t = 0; t < S; ++t) k_step<<<256, 512, 0, stream>>>(P, t);
  k_ar<<<256, 512, 0, stream>>>(P);
  k_dec<<<2048, 512, 0, stream>>>(P);
  k_out<<<1024, 512, 0, stream>>>(P);
}